// Round 1
// baseline (538.212 us; speedup 1.0000x reference)
//
#include <hip/hip_runtime.h>
#include <math.h>

#define N_PTS 8192
#define M_PTS 32768
#define CX    256
#define CSK   128
#define K1    384
#define HD    256

#define OUT_POS_OFF (M_PTS * HD)              // 8388608
#define OUT_B_OFF   (OUT_POS_OFF + M_PTS * 3) // 8486912

#define TM   32
#define AST  388   // LDS row stride (floats): 384+4, keeps 16B alignment, 4 mod 32 banks

// ---------------- kernel 0: pack ref points + squared norms ----------------
__global__ __launch_bounds__(256)
void prep_pp_kernel(const float* __restrict__ pos, float4* __restrict__ pospp) {
    int j = blockIdx.x * 256 + threadIdx.x;
    if (j >= N_PTS) return;
    float x = pos[3 * j + 0], y = pos[3 * j + 1], z = pos[3 * j + 2];
    // pp = (x*x + y*y) + z*z with per-op rounding (matches np.sum of elementwise squares)
    float pp = __fadd_rn(__fadd_rn(__fmul_rn(x, x), __fmul_rn(y, y)), __fmul_rn(z, z));
    pospp[j] = make_float4(x, y, z, pp);
}

// ---------------- kernel 1: KNN top-3 (split-scan + LDS merge) ----------------
__global__ __launch_bounds__(256)
void knn_kernel(const float4* __restrict__ pospp,
                const float*  __restrict__ pos_skip,
                float4* __restrict__ wq,
                int4*   __restrict__ iq) {
    __shared__ float sd[4][64][3];
    __shared__ int   si[4][64][3];
    const int lane = threadIdx.x & 63;
    const int wv   = threadIdx.x >> 6;           // wave 0..3 -> candidate quarter
    const int q    = blockIdx.x * 64 + lane;

    const float qx = pos_skip[3 * q + 0];
    const float qy = pos_skip[3 * q + 1];
    const float qz = pos_skip[3 * q + 2];
    const float qq = __fadd_rn(__fadd_rn(__fmul_rn(qx, qx), __fmul_rn(qy, qy)), __fmul_rn(qz, qz));

    float d0 = __builtin_inff(), d1 = __builtin_inff(), d2 = __builtin_inff();
    int   i0 = 0, i1 = 0, i2 = 0;

    const int jbeg = wv * (N_PTS / 4);
    const int jend = jbeg + (N_PTS / 4);
    #pragma unroll 8
    for (int j = jbeg; j < jend; ++j) {
        float4 c = pospp[j];
        // dot = fma chain; d2 = round((qq+pp) - 2*dot): 2*dot exact, fmaf(-2,dot,t) == round(t-2dot)
        float dot = __fmaf_rn(qz, c.z, __fmaf_rn(qy, c.y, __fmul_rn(qx, c.x)));
        float dd  = __fmaf_rn(-2.0f, dot, __fadd_rn(qq, c.w));
        dd = fmaxf(dd, 0.0f);
        if (dd < d2) {                 // strict <  => earliest index wins ties (lax.top_k)
            if (dd < d1) {
                d2 = d1; i2 = i1;
                if (dd < d0) { d1 = d0; i1 = i0; d0 = dd; i0 = j; }
                else         { d1 = dd; i1 = j; }
            } else { d2 = dd; i2 = j; }
        }
    }
    sd[wv][lane][0] = d0; sd[wv][lane][1] = d1; sd[wv][lane][2] = d2;
    si[wv][lane][0] = i0; si[wv][lane][1] = i1; si[wv][lane][2] = i2;
    __syncthreads();

    if (threadIdx.x < 64) {
        const int t = threadIdx.x;
        float e0 = __builtin_inff(), e1 = __builtin_inff(), e2 = __builtin_inff();
        int   j0 = 0, j1 = 0, j2 = 0;
        // feed splits in ascending index order; within split ascending distance
        #pragma unroll
        for (int ww = 0; ww < 4; ++ww) {
            #pragma unroll
            for (int k = 0; k < 3; ++k) {
                float dd = sd[ww][t][k];
                int   jj = si[ww][t][k];
                if (dd < e2) {
                    if (dd < e1) {
                        e2 = e1; j2 = j1;
                        if (dd < e0) { e1 = e0; j1 = j0; e0 = dd; j0 = jj; }
                        else         { e1 = dd; j1 = jj; }
                    } else { e2 = dd; j2 = jj; }
                }
            }
        }
        float w0 = 1.0f / (e0 + 1e-16f);
        float w1 = 1.0f / (e1 + 1e-16f);
        float w2 = 1.0f / (e2 + 1e-16f);
        float inv = 1.0f / ((w0 + w1) + w2);
        wq[blockIdx.x * 64 + t] = make_float4(w0 * inv, w1 * inv, w2 * inv, 0.0f);
        iq[blockIdx.x * 64 + t] = make_int4(j0, j1, j2, 0);
    }
}

// ---------------- kernel 2: gather-interp + concat + MLP (fused) ----------------
__global__ __launch_bounds__(256)
void fused_mlp_kernel(const float* __restrict__ x,
                      const float* __restrict__ x_skip,
                      const float4* __restrict__ wq,
                      const int4*  __restrict__ iq,
                      const float* __restrict__ W1, const float* __restrict__ b1,
                      const float* __restrict__ W2, const float* __restrict__ b2,
                      const float* __restrict__ pos_skip,
                      const int*   __restrict__ batch_skip,
                      float* __restrict__ out) {
    __shared__ float Ab[TM * AST];   // 49664 B; holds A [32][384], then reused for h1 [32][256]
    const int t  = threadIdx.x;
    const int tc = t & 31;           // col group (8 cols each)
    const int tr = t >> 5;           // row group (4 rows each)
    const int r0 = blockIdx.x * TM;

    // ---- phase 1a: knn-interpolated cols 0..255 (thread t = column t) ----
    #pragma unroll 4
    for (int r = 0; r < TM; ++r) {
        float4 wv = wq[r0 + r];      // uniform per r -> scalar loads
        int4   iv = iq[r0 + r];
        float v = (wv.x * x[iv.x * CX + t] + wv.y * x[iv.y * CX + t]) + wv.z * x[iv.z * CX + t];
        Ab[r * AST + t] = v;
    }
    // ---- phase 1b: skip cols 256..383 ----
    {
        const int c2 = t & 127, half = t >> 7;
        #pragma unroll 4
        for (int rr = 0; rr < 16; ++rr) {
            int r = half * 16 + rr;
            Ab[r * AST + CX + c2] = x_skip[(r0 + r) * CSK + c2];
        }
    }
    __syncthreads();

    // ---- phase 2: GEMM1  h1 = relu(A @ W1 + b1) ----
    float acc[4][8];
    {
        float bv[8];
        *(float4*)&bv[0] = *(const float4*)&b1[tc * 8];
        *(float4*)&bv[4] = *(const float4*)&b1[tc * 8 + 4];
        #pragma unroll
        for (int i = 0; i < 4; ++i)
            #pragma unroll
            for (int c = 0; c < 8; ++c) acc[i][c] = bv[c];
    }
    for (int k = 0; k < K1; k += 4) {
        float a[4][4];
        #pragma unroll
        for (int i = 0; i < 4; ++i)
            *(float4*)a[i] = *(const float4*)&Ab[(tr * 4 + i) * AST + k];
        #pragma unroll
        for (int kk = 0; kk < 4; ++kk) {
            float w8[8];
            *(float4*)&w8[0] = *(const float4*)&W1[(k + kk) * HD + tc * 8];
            *(float4*)&w8[4] = *(const float4*)&W1[(k + kk) * HD + tc * 8 + 4];
            #pragma unroll
            for (int i = 0; i < 4; ++i)
                #pragma unroll
                for (int c = 0; c < 8; ++c)
                    acc[i][c] = __fmaf_rn(a[i][kk], w8[c], acc[i][c]);
        }
    }
    __syncthreads();   // everyone done reading A
    #pragma unroll
    for (int i = 0; i < 4; ++i) {
        float v[8];
        #pragma unroll
        for (int c = 0; c < 8; ++c) v[c] = fmaxf(acc[i][c], 0.0f);
        *(float4*)&Ab[(tr * 4 + i) * AST + tc * 8]     = *(float4*)&v[0];
        *(float4*)&Ab[(tr * 4 + i) * AST + tc * 8 + 4] = *(float4*)&v[4];
    }
    __syncthreads();

    // ---- phase 3: GEMM2  h2 = h1 @ W2 + b2 ----
    float acc2[4][8];
    {
        float bv[8];
        *(float4*)&bv[0] = *(const float4*)&b2[tc * 8];
        *(float4*)&bv[4] = *(const float4*)&b2[tc * 8 + 4];
        #pragma unroll
        for (int i = 0; i < 4; ++i)
            #pragma unroll
            for (int c = 0; c < 8; ++c) acc2[i][c] = bv[c];
    }
    for (int k = 0; k < HD; k += 4) {
        float a[4][4];
        #pragma unroll
        for (int i = 0; i < 4; ++i)
            *(float4*)a[i] = *(const float4*)&Ab[(tr * 4 + i) * AST + k];
        #pragma unroll
        for (int kk = 0; kk < 4; ++kk) {
            float w8[8];
            *(float4*)&w8[0] = *(const float4*)&W2[(k + kk) * HD + tc * 8];
            *(float4*)&w8[4] = *(const float4*)&W2[(k + kk) * HD + tc * 8 + 4];
            #pragma unroll
            for (int i = 0; i < 4; ++i)
                #pragma unroll
                for (int c = 0; c < 8; ++c)
                    acc2[i][c] = __fmaf_rn(a[i][kk], w8[c], acc2[i][c]);
        }
    }

    // ---- epilogue: store h, plus pos_skip / batch_skip tails ----
    #pragma unroll
    for (int i = 0; i < 4; ++i) {
        int row = r0 + tr * 4 + i;
        *(float4*)&out[row * HD + tc * 8]     = *(float4*)&acc2[i][0];
        *(float4*)&out[row * HD + tc * 8 + 4] = *(float4*)&acc2[i][4];
    }
    if (t < TM * 3)
        out[OUT_POS_OFF + blockIdx.x * (TM * 3) + t] = pos_skip[blockIdx.x * (TM * 3) + t];
    if (t < TM)
        out[OUT_B_OFF + blockIdx.x * TM + t] = (float)batch_skip[blockIdx.x * TM + t];
}

// ---------------- launcher ----------------
extern "C" void kernel_launch(void* const* d_in, const int* in_sizes, int n_in,
                              void* d_out, int out_size, void* d_ws, size_t ws_size,
                              hipStream_t stream) {
    const float* x          = (const float*)d_in[0];
    const float* pos        = (const float*)d_in[1];
    // d_in[2] = batch (all handled as single graph; unused)
    const float* x_skip     = (const float*)d_in[3];
    const float* pos_skip   = (const float*)d_in[4];
    const int*   batch_skip = (const int*)d_in[5];
    const float* W1         = (const float*)d_in[6];
    const float* b1         = (const float*)d_in[7];
    const float* W2         = (const float*)d_in[8];
    const float* b2         = (const float*)d_in[9];
    float* out = (float*)d_out;

    // workspace layout
    float4* pospp = (float4*)d_ws;                                        // 8192*16 B
    float4* wq    = (float4*)((char*)d_ws + N_PTS * 16);                  // 32768*16 B
    int4*   iq    = (int4*)((char*)d_ws + N_PTS * 16 + M_PTS * 16);       // 32768*16 B

    prep_pp_kernel<<<N_PTS / 256, 256, 0, stream>>>(pos, pospp);
    knn_kernel<<<M_PTS / 64, 256, 0, stream>>>(pospp, pos_skip, wq, iq);
    fused_mlp_kernel<<<M_PTS / TM, 256, 0, stream>>>(x, x_skip, wq, iq,
                                                     W1, b1, W2, b2,
                                                     pos_skip, batch_skip, out);
}

// Round 3
// 515.272 us; speedup vs baseline: 1.0445x; 1.0445x over previous
//
#include <hip/hip_runtime.h>
#include <math.h>

#define N_PTS 8192
#define M_PTS 32768
#define CX    256
#define CSK   128
#define K1    384
#define HD    256

#define OUT_POS_OFF (M_PTS * HD)              // 8388608
#define OUT_B_OFF   (OUT_POS_OFF + M_PTS * 3) // 8486912

#define SPLITS 16  // candidate splits per query-group (16 waves/block)
#define TM     16  // MLP rows per block
#define AST    388 // LDS row stride (floats): 384+4, 16B-aligned rows

// ---------------- kernel 0: pack ref points + squared norms ----------------
__global__ __launch_bounds__(256)
void prep_pp_kernel(const float* __restrict__ pos, float4* __restrict__ pospp) {
    int j = blockIdx.x * 256 + threadIdx.x;
    if (j >= N_PTS) return;
    float x = pos[3 * j + 0], y = pos[3 * j + 1], z = pos[3 * j + 2];
    float pp = __fadd_rn(__fadd_rn(__fmul_rn(x, x), __fmul_rn(y, y)), __fmul_rn(z, z));
    pospp[j] = make_float4(x, y, z, pp);
}

// ---------------- kernel 1: KNN top-3 (16-way split-scan + LDS merge) ----------------
__global__ __launch_bounds__(1024)
void knn_kernel(const float4* __restrict__ pospp,
                const float*  __restrict__ pos_skip,
                float4* __restrict__ wq,
                int4*   __restrict__ iq) {
    __shared__ float sd[SPLITS][64][3];
    __shared__ int   si[SPLITS][64][3];
    const int lane = threadIdx.x & 63;
    const int wv   = threadIdx.x >> 6;           // wave 0..15 -> candidate slice
    const int q    = blockIdx.x * 64 + lane;

    const float qx = pos_skip[3 * q + 0];
    const float qy = pos_skip[3 * q + 1];
    const float qz = pos_skip[3 * q + 2];
    const float qq = __fadd_rn(__fadd_rn(__fmul_rn(qx, qx), __fmul_rn(qy, qy)), __fmul_rn(qz, qz));

    float d0 = __builtin_inff(), d1 = __builtin_inff(), d2 = __builtin_inff();
    int   i0 = 0, i1 = 0, i2 = 0;

    const int jbeg = wv * (N_PTS / SPLITS);
    const int jend = jbeg + (N_PTS / SPLITS);
    #pragma unroll 8
    for (int j = jbeg; j < jend; ++j) {
        float4 c = pospp[j];
        // dot = fma chain; dd = round((qq+pp) - 2*dot): 2*dot exact => matches np order
        float dot = __fmaf_rn(qz, c.z, __fmaf_rn(qy, c.y, __fmul_rn(qx, c.x)));
        float dd  = __fmaf_rn(-2.0f, dot, __fadd_rn(qq, c.w));
        dd = fmaxf(dd, 0.0f);
        if (dd < d2) {                 // strict <  => earliest index wins ties
            if (dd < d1) {
                d2 = d1; i2 = i1;
                if (dd < d0) { d1 = d0; i1 = i0; d0 = dd; i0 = j; }
                else         { d1 = dd; i1 = j; }
            } else { d2 = dd; i2 = j; }
        }
    }
    sd[wv][lane][0] = d0; sd[wv][lane][1] = d1; sd[wv][lane][2] = d2;
    si[wv][lane][0] = i0; si[wv][lane][1] = i1; si[wv][lane][2] = i2;
    __syncthreads();

    if (threadIdx.x < 64) {
        const int t = threadIdx.x;
        float e0 = __builtin_inff(), e1 = __builtin_inff(), e2 = __builtin_inff();
        int   j0 = 0, j1 = 0, j2 = 0;
        // feed splits in ascending index order; within split ascending distance
        #pragma unroll
        for (int ww = 0; ww < SPLITS; ++ww) {
            #pragma unroll
            for (int k = 0; k < 3; ++k) {
                float dd = sd[ww][t][k];
                int   jj = si[ww][t][k];
                if (dd < e2) {
                    if (dd < e1) {
                        e2 = e1; j2 = j1;
                        if (dd < e0) { e1 = e0; j1 = j0; e0 = dd; j0 = jj; }
                        else         { e1 = dd; j1 = jj; }
                    } else { e2 = dd; j2 = jj; }
                }
            }
        }
        float w0 = 1.0f / (e0 + 1e-16f);
        float w1 = 1.0f / (e1 + 1e-16f);
        float w2 = 1.0f / (e2 + 1e-16f);
        float inv = 1.0f / ((w0 + w1) + w2);
        wq[blockIdx.x * 64 + t] = make_float4(w0 * inv, w1 * inv, w2 * inv, 0.0f);
        iq[blockIdx.x * 64 + t] = make_int4(j0, j1, j2, 0);
    }
}

// ---------------- kernel 2: gather-interp + concat + MLP (fused) ----------------
__global__ __launch_bounds__(256)
void fused_mlp_kernel(const float* __restrict__ x,
                      const float* __restrict__ x_skip,
                      const float4* __restrict__ wq,
                      const int4*  __restrict__ iq,
                      const float* __restrict__ W1, const float* __restrict__ b1,
                      const float* __restrict__ W2, const float* __restrict__ b2,
                      const float* __restrict__ pos_skip,
                      const int*   __restrict__ batch_skip,
                      float* __restrict__ out) {
    __shared__ float Ab[TM * AST];   // 24832 B -> 6 blocks/CU (24 waves, 75% occ)
    const int t  = threadIdx.x;
    const int tc = t & 31;           // col group (8 cols each)
    const int tr = t >> 5;           // row group (2 rows each, 0..7)
    const int r0 = blockIdx.x * TM;

    // ---- phase 1a: knn-interpolated cols 0..255 (thread t = column t) ----
    #pragma unroll 4
    for (int r = 0; r < TM; ++r) {
        float4 wv = wq[r0 + r];      // uniform per r
        int4   iv = iq[r0 + r];
        float v = (wv.x * x[iv.x * CX + t] + wv.y * x[iv.y * CX + t]) + wv.z * x[iv.z * CX + t];
        Ab[r * AST + t] = v;
    }
    // ---- phase 1b: skip cols 256..383 ----
    {
        const int c2 = t & 127, half = t >> 7;
        #pragma unroll
        for (int rr = 0; rr < TM / 2; ++rr) {
            int r = half * (TM / 2) + rr;
            Ab[r * AST + CX + c2] = x_skip[(r0 + r) * CSK + c2];
        }
    }
    __syncthreads();

    // ---- phase 2: GEMM1  h1 = relu(A @ W1 + b1) ----
    float acc[2][8];
    {
        float bv[8];
        *(float4*)&bv[0] = *(const float4*)&b1[tc * 8];
        *(float4*)&bv[4] = *(const float4*)&b1[tc * 8 + 4];
        #pragma unroll
        for (int i = 0; i < 2; ++i)
            #pragma unroll
            for (int c = 0; c < 8; ++c) acc[i][c] = bv[c];
    }
    for (int k = 0; k < K1; k += 4) {
        float a[2][4];
        #pragma unroll
        for (int i = 0; i < 2; ++i)
            *(float4*)a[i] = *(const float4*)&Ab[(tr * 2 + i) * AST + k];
        #pragma unroll
        for (int kk = 0; kk < 4; ++kk) {
            float w8[8];
            *(float4*)&w8[0] = *(const float4*)&W1[(k + kk) * HD + tc * 8];
            *(float4*)&w8[4] = *(const float4*)&W1[(k + kk) * HD + tc * 8 + 4];
            #pragma unroll
            for (int i = 0; i < 2; ++i)
                #pragma unroll
                for (int c = 0; c < 8; ++c)
                    acc[i][c] = __fmaf_rn(a[i][kk], w8[c], acc[i][c]);
        }
    }
    __syncthreads();   // everyone done reading A
    #pragma unroll
    for (int i = 0; i < 2; ++i) {
        float v[8];
        #pragma unroll
        for (int c = 0; c < 8; ++c) v[c] = fmaxf(acc[i][c], 0.0f);
        *(float4*)&Ab[(tr * 2 + i) * AST + tc * 8]     = *(float4*)&v[0];
        *(float4*)&Ab[(tr * 2 + i) * AST + tc * 8 + 4] = *(float4*)&v[4];
    }
    __syncthreads();

    // ---- phase 3: GEMM2  h2 = h1 @ W2 + b2 ----
    float acc2[2][8];
    {
        float bv[8];
        *(float4*)&bv[0] = *(const float4*)&b2[tc * 8];
        *(float4*)&bv[4] = *(const float4*)&b2[tc * 8 + 4];
        #pragma unroll
        for (int i = 0; i < 2; ++i)
            #pragma unroll
            for (int c = 0; c < 8; ++c) acc2[i][c] = bv[c];
    }
    for (int k = 0; k < HD; k += 4) {
        float a[2][4];
        #pragma unroll
        for (int i = 0; i < 2; ++i)
            *(float4*)a[i] = *(const float4*)&Ab[(tr * 2 + i) * AST + k];
        #pragma unroll
        for (int kk = 0; kk < 4; ++kk) {
            float w8[8];
            *(float4*)&w8[0] = *(const float4*)&W2[(k + kk) * HD + tc * 8];
            *(float4*)&w8[4] = *(const float4*)&W2[(k + kk) * HD + tc * 8 + 4];
            #pragma unroll
            for (int i = 0; i < 2; ++i)
                #pragma unroll
                for (int c = 0; c < 8; ++c)
                    acc2[i][c] = __fmaf_rn(a[i][kk], w8[c], acc2[i][c]);
        }
    }

    // ---- epilogue: store h, plus pos_skip / batch_skip tails ----
    #pragma unroll
    for (int i = 0; i < 2; ++i) {
        int row = r0 + tr * 2 + i;
        *(float4*)&out[row * HD + tc * 8]     = *(float4*)&acc2[i][0];
        *(float4*)&out[row * HD + tc * 8 + 4] = *(float4*)&acc2[i][4];
    }
    if (t < TM * 3)
        out[OUT_POS_OFF + blockIdx.x * (TM * 3) + t] = pos_skip[blockIdx.x * (TM * 3) + t];
    if (t < TM)
        out[OUT_B_OFF + blockIdx.x * TM + t] = (float)batch_skip[blockIdx.x * TM + t];
}

// ---------------- launcher ----------------
extern "C" void kernel_launch(void* const* d_in, const int* in_sizes, int n_in,
                              void* d_out, int out_size, void* d_ws, size_t ws_size,
                              hipStream_t stream) {
    const float* x          = (const float*)d_in[0];
    const float* pos        = (const float*)d_in[1];
    const float* x_skip     = (const float*)d_in[3];
    const float* pos_skip   = (const float*)d_in[4];
    const int*   batch_skip = (const int*)d_in[5];
    const float* W1         = (const float*)d_in[6];
    const float* b1         = (const float*)d_in[7];
    const float* W2         = (const float*)d_in[8];
    const float* b2         = (const float*)d_in[9];
    float* out = (float*)d_out;

    float4* pospp = (float4*)d_ws;
    float4* wq    = (float4*)((char*)d_ws + N_PTS * 16);
    int4*   iq    = (int4*)((char*)d_ws + N_PTS * 16 + M_PTS * 16);

    prep_pp_kernel<<<N_PTS / 256, 256, 0, stream>>>(pos, pospp);
    knn_kernel<<<M_PTS / 64, 1024, 0, stream>>>(pospp, pos_skip, wq, iq);
    fused_mlp_kernel<<<M_PTS / TM, 256, 0, stream>>>(x, x_skip, wq, iq,
                                                     W1, b1, W2, b2,
                                                     pos_skip, batch_skip, out);
}

// Round 4
// 377.637 us; speedup vs baseline: 1.4252x; 1.3645x over previous
//
#include <hip/hip_runtime.h>
#include <math.h>

#define N_PTS 8192
#define M_PTS 32768
#define CX    256
#define CSK   128
#define KD1   384
#define HD    256

#define OUT_POS_OFF (M_PTS * HD)              // 8388608
#define OUT_B_OFF   (OUT_POS_OFF + M_PTS * 3) // 8486912

#define SPLITS 16
#define TMF    64   // MLP rows per block
#define KC     64   // K chunk

using short8 = __attribute__((ext_vector_type(8))) short;
using f32x4  = __attribute__((ext_vector_type(4))) float;

__device__ __forceinline__ unsigned short f2bf(float f) {
    unsigned int u = __float_as_uint(f);
    return (unsigned short)((u + 0x7FFFu + ((u >> 16) & 1u)) >> 16);
}
__device__ __forceinline__ float bf2f(unsigned short h) {
    return __uint_as_float(((unsigned int)h) << 16);
}

// ---------------- kernel 0a: pack ref points + squared norms ----------------
__global__ __launch_bounds__(256)
void prep_pp_kernel(const float* __restrict__ pos, float4* __restrict__ pospp) {
    int j = blockIdx.x * 256 + threadIdx.x;
    if (j >= N_PTS) return;
    float x = pos[3 * j + 0], y = pos[3 * j + 1], z = pos[3 * j + 2];
    float pp = __fadd_rn(__fadd_rn(__fmul_rn(x, x), __fmul_rn(y, y)), __fmul_rn(z, z));
    pospp[j] = make_float4(x, y, z, pp);
}

// ---------------- kernel 0b: split + transpose W1/W2 to bf16 hi/lo [col][k] ----------------
__global__ __launch_bounds__(256)
void prep_w_kernel(const float* __restrict__ W1, const float* __restrict__ W2,
                   unsigned short* __restrict__ w1h, unsigned short* __restrict__ w1l,
                   unsigned short* __restrict__ w2h, unsigned short* __restrict__ w2l) {
    int id = blockIdx.x * 256 + threadIdx.x;
    if (id < 256 * KD1) {
        int col = id / KD1, k = id % KD1;
        float v = W1[k * HD + col];
        unsigned short h = f2bf(v);
        w1h[id] = h;
        w1l[id] = f2bf(v - bf2f(h));
    } else {
        int id2 = id - 256 * KD1;
        if (id2 < 256 * 256) {
            int col = id2 >> 8, k = id2 & 255;
            float v = W2[k * HD + col];
            unsigned short h = f2bf(v);
            w2h[id2] = h;
            w2l[id2] = f2bf(v - bf2f(h));
        }
    }
}

// ---------------- kernel 1: KNN top-3 (16-way split, batched branchless scan) ----------------
__global__ __launch_bounds__(1024)
void knn_kernel(const float4* __restrict__ pospp,
                const float*  __restrict__ pos_skip,
                float4* __restrict__ wq,
                int4*   __restrict__ iq) {
    __shared__ float sd[SPLITS][64][3];
    __shared__ int   si[SPLITS][64][3];
    const int lane = threadIdx.x & 63;
    const int wv   = threadIdx.x >> 6;
    const int q    = blockIdx.x * 64 + lane;

    const float qx = pos_skip[3 * q + 0];
    const float qy = pos_skip[3 * q + 1];
    const float qz = pos_skip[3 * q + 2];
    const float qq = __fadd_rn(__fadd_rn(__fmul_rn(qx, qx), __fmul_rn(qy, qy)), __fmul_rn(qz, qz));

    float d0 = __builtin_inff(), d1 = __builtin_inff(), d2 = __builtin_inff();
    int   i0 = 0, i1 = 0, i2 = 0;

    const int jbeg = wv * (N_PTS / SPLITS);
    const int jend = jbeg + (N_PTS / SPLITS);
    for (int j = jbeg; j < jend; j += 8) {
        float4 cc[8];
        #pragma unroll
        for (int u = 0; u < 8; ++u) cc[u] = pospp[j + u];
        #pragma unroll
        for (int u = 0; u < 8; ++u) {
            float dot = __fmaf_rn(qz, cc[u].z, __fmaf_rn(qy, cc[u].y, __fmul_rn(qx, cc[u].x)));
            float dd  = __fmaf_rn(-2.0f, dot, __fadd_rn(qq, cc[u].w));
            dd = fmaxf(dd, 0.0f);
            int jj = j + u;
            bool l2 = dd < d2, l1 = dd < d1, l0 = dd < d0;
            float nd2 = l1 ? d1 : (l2 ? dd : d2); int ni2 = l1 ? i1 : (l2 ? jj : i2);
            float nd1 = l0 ? d0 : (l1 ? dd : d1); int ni1 = l0 ? i0 : (l1 ? jj : i1);
            float nd0 = l0 ? dd : d0;             int ni0 = l0 ? jj : i0;
            d2 = nd2; i2 = ni2; d1 = nd1; i1 = ni1; d0 = nd0; i0 = ni0;
        }
    }
    sd[wv][lane][0] = d0; sd[wv][lane][1] = d1; sd[wv][lane][2] = d2;
    si[wv][lane][0] = i0; si[wv][lane][1] = i1; si[wv][lane][2] = i2;
    __syncthreads();

    if (threadIdx.x < 64) {
        const int t = threadIdx.x;
        float e0 = __builtin_inff(), e1 = __builtin_inff(), e2 = __builtin_inff();
        int   j0 = 0, j1 = 0, j2 = 0;
        #pragma unroll
        for (int ww = 0; ww < SPLITS; ++ww) {
            #pragma unroll
            for (int k = 0; k < 3; ++k) {
                float dd = sd[ww][t][k];
                int   jj = si[ww][t][k];
                if (dd < e2) {
                    if (dd < e1) {
                        e2 = e1; j2 = j1;
                        if (dd < e0) { e1 = e0; j1 = j0; e0 = dd; j0 = jj; }
                        else         { e1 = dd; j1 = jj; }
                    } else { e2 = dd; j2 = jj; }
                }
            }
        }
        float w0 = 1.0f / (e0 + 1e-16f);
        float w1 = 1.0f / (e1 + 1e-16f);
        float w2 = 1.0f / (e2 + 1e-16f);
        float inv = 1.0f / ((w0 + w1) + w2);
        wq[blockIdx.x * 64 + t] = make_float4(w0 * inv, w1 * inv, w2 * inv, 0.0f);
        iq[blockIdx.x * 64 + t] = make_int4(j0, j1, j2, 0);
    }
}

// ---------------- kernel 2: gather-interp + concat + MLP via bf16-split MFMA ----------------
__global__ __launch_bounds__(256, 2)
void mfma_mlp_kernel(const float* __restrict__ x,
                     const float* __restrict__ x_skip,
                     const float4* __restrict__ wq,
                     const int4*  __restrict__ iq,
                     const unsigned short* __restrict__ W1h, const unsigned short* __restrict__ W1l,
                     const unsigned short* __restrict__ W2h, const unsigned short* __restrict__ W2l,
                     const float* __restrict__ b1, const float* __restrict__ b2,
                     const float* __restrict__ pos_skip, const int* __restrict__ batch_skip,
                     float* __restrict__ out) {
    __shared__ unsigned short Whi[256 * 64];  // [col][k] swizzled, 32KB
    __shared__ unsigned short Wlo[256 * 64];  // 32KB
    __shared__ unsigned short Ahi[64 * 64];   // [row][k] swizzled, 8KB
    __shared__ unsigned short Alo[64 * 64];   // 8KB

    const int t    = threadIdx.x;
    const int lane = t & 63;
    const int w    = t >> 6;
    const int r0   = blockIdx.x * TMF;

    // A-write geometry: thread t -> row t>>2, k-group (t&3)*16
    const int ar    = t >> 2;
    const int akg   = t & 3;
    const int abase = ar * 128 + akg * 32;
    const int aswz  = (ar & 7) << 4;
    const int aoff0 = (abase ^ aswz) >> 1;
    const int aoff1 = ((abase + 16) ^ aswz) >> 1;

    const float4 wv = wq[r0 + ar];
    const int4   iv = iq[r0 + ar];

    // W staging geometry: per round, thread t copies 16B; slot = rd*4096 + t*16
    const int wcol0 = t >> 3;          // + rd*32
    const int wi16  = t & 7;
    const int wswz  = ((t >> 3) & 7) << 4;
    const int wlds0 = ((t * 16) ^ wswz) >> 1;  // + rd*2048 (ushort idx)

    // ---- GEMM1 accumulators, bias init ----
    f32x4 acc1[4][4];
    #pragma unroll
    for (int cb = 0; cb < 4; ++cb) {
        float bv = b1[w * 64 + cb * 16 + (lane & 15)];
        #pragma unroll
        for (int rb = 0; rb < 4; ++rb) acc1[rb][cb] = (f32x4){bv, bv, bv, bv};
    }

    // ---- GEMM1: K=384, 6 chunks of 64 ----
    for (int c = 0; c < 6; ++c) {
        const int kbase = c * KC;
        // A chunk: interp (cols<256) or skip copy, split, swizzled LDS write
        {
            float vv[16];
            const int col0 = kbase + akg * 16;
            if (col0 < 256) {
                const float4* xa = (const float4*)&x[(size_t)iv.x * CX + col0];
                const float4* xb = (const float4*)&x[(size_t)iv.y * CX + col0];
                const float4* xc = (const float4*)&x[(size_t)iv.z * CX + col0];
                #pragma unroll
                for (int q4 = 0; q4 < 4; ++q4) {
                    float4 a4 = xa[q4], b4 = xb[q4], c4 = xc[q4];
                    vv[q4 * 4 + 0] = (wv.x * a4.x + wv.y * b4.x) + wv.z * c4.x;
                    vv[q4 * 4 + 1] = (wv.x * a4.y + wv.y * b4.y) + wv.z * c4.y;
                    vv[q4 * 4 + 2] = (wv.x * a4.z + wv.y * b4.z) + wv.z * c4.z;
                    vv[q4 * 4 + 3] = (wv.x * a4.w + wv.y * b4.w) + wv.z * c4.w;
                }
            } else {
                const float4* xs = (const float4*)&x_skip[(size_t)(r0 + ar) * CSK + (col0 - 256)];
                #pragma unroll
                for (int q4 = 0; q4 < 4; ++q4) {
                    float4 s4 = xs[q4];
                    vv[q4 * 4 + 0] = s4.x; vv[q4 * 4 + 1] = s4.y;
                    vv[q4 * 4 + 2] = s4.z; vv[q4 * 4 + 3] = s4.w;
                }
            }
            short8 h0, h1v, l0v, l1v;
            #pragma unroll
            for (int e = 0; e < 8; ++e) {
                unsigned short hh = f2bf(vv[e]);
                h0[e] = (short)hh; l0v[e] = (short)f2bf(vv[e] - bf2f(hh));
            }
            #pragma unroll
            for (int e = 0; e < 8; ++e) {
                unsigned short hh = f2bf(vv[8 + e]);
                h1v[e] = (short)hh; l1v[e] = (short)f2bf(vv[8 + e] - bf2f(hh));
            }
            *(short8*)&Ahi[aoff0] = h0;  *(short8*)&Ahi[aoff1] = h1v;
            *(short8*)&Alo[aoff0] = l0v; *(short8*)&Alo[aoff1] = l1v;
        }
        // W1 chunk staging (reg-staged, swizzled LDS write)
        #pragma unroll
        for (int rd = 0; rd < 8; ++rd) {
            int col = rd * 32 + wcol0;
            size_t g = (size_t)col * KD1 + kbase + wi16 * 8;
            *(short8*)&Whi[rd * 2048 + wlds0] = *(const short8*)&W1h[g];
            *(short8*)&Wlo[rd * 2048 + wlds0] = *(const short8*)&W1l[g];
        }
        __syncthreads();
        // MFMA: 3-term bf16 split
        short8 ah[4][2], al[4][2];
        #pragma unroll
        for (int rb = 0; rb < 4; ++rb)
            #pragma unroll
            for (int ks = 0; ks < 2; ++ks) {
                int row = rb * 16 + (lane & 15);
                int ba  = (row * 128 + ks * 64 + ((lane >> 4) << 4)) ^ ((lane & 7) << 4);
                ah[rb][ks] = *(const short8*)&Ahi[ba >> 1];
                al[rb][ks] = *(const short8*)&Alo[ba >> 1];
            }
        #pragma unroll
        for (int cb = 0; cb < 4; ++cb) {
            short8 bh[2], bl[2];
            #pragma unroll
            for (int ks = 0; ks < 2; ++ks) {
                int col = w * 64 + cb * 16 + (lane & 15);
                int bb  = (col * 128 + ks * 64 + ((lane >> 4) << 4)) ^ ((lane & 7) << 4);
                bh[ks] = *(const short8*)&Whi[bb >> 1];
                bl[ks] = *(const short8*)&Wlo[bb >> 1];
            }
            #pragma unroll
            for (int rb = 0; rb < 4; ++rb)
                #pragma unroll
                for (int ks = 0; ks < 2; ++ks) {
                    acc1[rb][cb] = __builtin_amdgcn_mfma_f32_16x16x32_bf16(ah[rb][ks], bh[ks], acc1[rb][cb], 0, 0, 0);
                    acc1[rb][cb] = __builtin_amdgcn_mfma_f32_16x16x32_bf16(al[rb][ks], bh[ks], acc1[rb][cb], 0, 0, 0);
                    acc1[rb][cb] = __builtin_amdgcn_mfma_f32_16x16x32_bf16(ah[rb][ks], bl[ks], acc1[rb][cb], 0, 0, 0);
                }
        }
        __syncthreads();
    }

    // ---- relu + bf16 split of h1, packed in regs ----
    unsigned int h1h[32], h1l[32];
    #pragma unroll
    for (int rb = 0; rb < 4; ++rb)
        #pragma unroll
        for (int cb = 0; cb < 4; ++cb)
            #pragma unroll
            for (int r = 0; r < 4; ++r) {
                int id = (rb * 4 + cb) * 4 + r;
                float hv = fmaxf(acc1[rb][cb][r], 0.0f);
                unsigned short hh = f2bf(hv);
                unsigned short hl = f2bf(hv - bf2f(hh));
                if ((id & 1) == 0) { h1h[id >> 1] = hh; h1l[id >> 1] = hl; }
                else { h1h[id >> 1] |= ((unsigned int)hh) << 16; h1l[id >> 1] |= ((unsigned int)hl) << 16; }
            }

    // ---- GEMM2 accumulators, bias init ----
    f32x4 acc2[4][4];
    #pragma unroll
    for (int cb = 0; cb < 4; ++cb) {
        float bv = b2[w * 64 + cb * 16 + (lane & 15)];
        #pragma unroll
        for (int rb = 0; rb < 4; ++rb) acc2[rb][cb] = (f32x4){bv, bv, bv, bv};
    }

    // ---- GEMM2: K=256, 4 chunks of 64; chunk c's A = wave c's h1 tile ----
    for (int c = 0; c < 4; ++c) {
        const int kbase = c * KC;
        #pragma unroll
        for (int rd = 0; rd < 8; ++rd) {
            int col = rd * 32 + wcol0;
            size_t g = (size_t)col * 256 + kbase + wi16 * 8;
            *(short8*)&Whi[rd * 2048 + wlds0] = *(const short8*)&W2h[g];
            *(short8*)&Wlo[rd * 2048 + wlds0] = *(const short8*)&W2l[g];
        }
        if (w == c) {
            #pragma unroll
            for (int rb = 0; rb < 4; ++rb)
                #pragma unroll
                for (int cb = 0; cb < 4; ++cb)
                    #pragma unroll
                    for (int r = 0; r < 4; ++r) {
                        int id = (rb * 4 + cb) * 4 + r;
                        unsigned short hh = (unsigned short)(h1h[id >> 1] >> ((id & 1) * 16));
                        unsigned short hl = (unsigned short)(h1l[id >> 1] >> ((id & 1) * 16));
                        int row = rb * 16 + (lane >> 4) * 4 + r;
                        int kl  = cb * 16 + (lane & 15);
                        int ba  = (row * 128 + kl * 2) ^ ((row & 7) << 4);
                        Ahi[ba >> 1] = hh;
                        Alo[ba >> 1] = hl;
                    }
        }
        __syncthreads();
        short8 ah[4][2], al[4][2];
        #pragma unroll
        for (int rb = 0; rb < 4; ++rb)
            #pragma unroll
            for (int ks = 0; ks < 2; ++ks) {
                int row = rb * 16 + (lane & 15);
                int ba  = (row * 128 + ks * 64 + ((lane >> 4) << 4)) ^ ((lane & 7) << 4);
                ah[rb][ks] = *(const short8*)&Ahi[ba >> 1];
                al[rb][ks] = *(const short8*)&Alo[ba >> 1];
            }
        #pragma unroll
        for (int cb = 0; cb < 4; ++cb) {
            short8 bh[2], bl[2];
            #pragma unroll
            for (int ks = 0; ks < 2; ++ks) {
                int col = w * 64 + cb * 16 + (lane & 15);
                int bb  = (col * 128 + ks * 64 + ((lane >> 4) << 4)) ^ ((lane & 7) << 4);
                bh[ks] = *(const short8*)&Whi[bb >> 1];
                bl[ks] = *(const short8*)&Wlo[bb >> 1];
            }
            #pragma unroll
            for (int rb = 0; rb < 4; ++rb)
                #pragma unroll
                for (int ks = 0; ks < 2; ++ks) {
                    acc2[rb][cb] = __builtin_amdgcn_mfma_f32_16x16x32_bf16(ah[rb][ks], bh[ks], acc2[rb][cb], 0, 0, 0);
                    acc2[rb][cb] = __builtin_amdgcn_mfma_f32_16x16x32_bf16(al[rb][ks], bh[ks], acc2[rb][cb], 0, 0, 0);
                    acc2[rb][cb] = __builtin_amdgcn_mfma_f32_16x16x32_bf16(ah[rb][ks], bl[ks], acc2[rb][cb], 0, 0, 0);
                }
        }
        __syncthreads();
    }

    // ---- epilogue ----
    #pragma unroll
    for (int rb = 0; rb < 4; ++rb)
        #pragma unroll
        for (int cb = 0; cb < 4; ++cb)
            #pragma unroll
            for (int r = 0; r < 4; ++r) {
                int row = r0 + rb * 16 + (lane >> 4) * 4 + r;
                int col = w * 64 + cb * 16 + (lane & 15);
                out[(size_t)row * HD + col] = acc2[rb][cb][r];
            }
    if (t < TMF * 3)
        out[OUT_POS_OFF + blockIdx.x * (TMF * 3) + t] = pos_skip[blockIdx.x * (TMF * 3) + t];
    if (t < TMF)
        out[OUT_B_OFF + blockIdx.x * TMF + t] = (float)batch_skip[blockIdx.x * TMF + t];
}

// ---------------- launcher ----------------
extern "C" void kernel_launch(void* const* d_in, const int* in_sizes, int n_in,
                              void* d_out, int out_size, void* d_ws, size_t ws_size,
                              hipStream_t stream) {
    const float* x          = (const float*)d_in[0];
    const float* pos        = (const float*)d_in[1];
    const float* x_skip     = (const float*)d_in[3];
    const float* pos_skip   = (const float*)d_in[4];
    const int*   batch_skip = (const int*)d_in[5];
    const float* W1         = (const float*)d_in[6];
    const float* b1         = (const float*)d_in[7];
    const float* W2         = (const float*)d_in[8];
    const float* b2         = (const float*)d_in[9];
    float* out = (float*)d_out;

    char* ws = (char*)d_ws;
    float4* pospp        = (float4*)(ws);                       // 131072 B
    float4* wq           = (float4*)(ws + 131072);              // 524288 B
    int4*   iq           = (int4*)(ws + 655360);                // 524288 B
    unsigned short* w1h  = (unsigned short*)(ws + 1179648);     // 196608 B
    unsigned short* w1l  = (unsigned short*)(ws + 1376256);     // 196608 B
    unsigned short* w2h  = (unsigned short*)(ws + 1572864);     // 131072 B
    unsigned short* w2l  = (unsigned short*)(ws + 1703936);     // 131072 B -> ends 1835008

    prep_pp_kernel<<<N_PTS / 256, 256, 0, stream>>>(pos, pospp);
    prep_w_kernel<<<(256 * KD1 + 256 * 256 + 255) / 256, 256, 0, stream>>>(W1, W2, w1h, w1l, w2h, w2l);
    knn_kernel<<<M_PTS / 64, 1024, 0, stream>>>(pospp, pos_skip, wq, iq);
    mfma_mlp_kernel<<<M_PTS / TMF, 256, 0, stream>>>(x, x_skip, wq, iq,
                                                     w1h, w1l, w2h, w2l, b1, b2,
                                                     pos_skip, batch_skip, out);
}

// Round 5
// 296.711 us; speedup vs baseline: 1.8139x; 1.2727x over previous
//
#include <hip/hip_runtime.h>
#include <math.h>

#define N_PTS 8192
#define M_PTS 32768
#define CX    256
#define CSK   128
#define KD1   384
#define HD    256

#define OUT_POS_OFF (M_PTS * HD)              // 8388608
#define OUT_B_OFF   (OUT_POS_OFF + M_PTS * 3) // 8486912

#define SPLITS 16
#define TMF    64   // MLP rows per block
#define KC     32   // K chunk
#define NC1    12   // GEMM1 chunks (384/32)
#define NC2    8    // GEMM2 chunks (256/32)

using short8 = __attribute__((ext_vector_type(8))) short;
using f32x4  = __attribute__((ext_vector_type(4))) float;

__device__ __forceinline__ unsigned short f2bf(float f) {
    unsigned int u = __float_as_uint(f);
    return (unsigned short)((u + 0x7FFFu + ((u >> 16) & 1u)) >> 16);
}
__device__ __forceinline__ float bf2f(unsigned short h) {
    return __uint_as_float(((unsigned int)h) << 16);
}

// ---------------- kernel 0a: pack ref points + squared norms ----------------
__global__ __launch_bounds__(256)
void prep_pp_kernel(const float* __restrict__ pos, float4* __restrict__ pospp) {
    int j = blockIdx.x * 256 + threadIdx.x;
    if (j >= N_PTS) return;
    float x = pos[3 * j + 0], y = pos[3 * j + 1], z = pos[3 * j + 2];
    float pp = __fadd_rn(__fadd_rn(__fmul_rn(x, x), __fmul_rn(y, y)), __fmul_rn(z, z));
    pospp[j] = make_float4(x, y, z, pp);
}

// -------- kernel 0b: split W1/W2 to bf16 hi/lo, TILED [chunk][col][klocal] --------
__global__ __launch_bounds__(256)
void prep_w_kernel(const float* __restrict__ W1, const float* __restrict__ W2,
                   unsigned short* __restrict__ w1h, unsigned short* __restrict__ w1l,
                   unsigned short* __restrict__ w2h, unsigned short* __restrict__ w2l) {
    int id = blockIdx.x * 256 + threadIdx.x;
    if (id < 256 * KD1) {                       // 98304 = 12 chunks * 8192
        int c = id >> 13, rem = id & 8191;
        int col = rem >> 5, kl = rem & 31;
        float v = W1[(c * 32 + kl) * HD + col];
        unsigned short h = f2bf(v);
        w1h[id] = h;
        w1l[id] = f2bf(v - bf2f(h));
    } else if (id < 256 * KD1 + 256 * 256) {    // + 65536 = 8 chunks * 8192
        int id2 = id - 256 * KD1;
        int c = id2 >> 13, rem = id2 & 8191;
        int col = rem >> 5, kl = rem & 31;
        float v = W2[(c * 32 + kl) * HD + col];
        unsigned short h = f2bf(v);
        w2h[id2] = h;
        w2l[id2] = f2bf(v - bf2f(h));
    }
}

// ---------------- kernel 1: KNN top-3 (16-way split, batch-8 + branchy insert) ----------------
__global__ __launch_bounds__(1024, 8)
void knn_kernel(const float4* __restrict__ pospp,
                const float*  __restrict__ pos_skip,
                float4* __restrict__ wq,
                int4*   __restrict__ iq) {
    __shared__ float sd[SPLITS][64][3];
    __shared__ int   si[SPLITS][64][3];
    const int lane = threadIdx.x & 63;
    const int wv   = threadIdx.x >> 6;
    const int q    = blockIdx.x * 64 + lane;

    const float qx = pos_skip[3 * q + 0];
    const float qy = pos_skip[3 * q + 1];
    const float qz = pos_skip[3 * q + 2];
    const float qq = __fadd_rn(__fadd_rn(__fmul_rn(qx, qx), __fmul_rn(qy, qy)), __fmul_rn(qz, qz));

    float d0 = __builtin_inff(), d1 = __builtin_inff(), d2 = __builtin_inff();
    int   i0 = 0, i1 = 0, i2 = 0;

    const int jbeg = wv * (N_PTS / SPLITS);
    const int jend = jbeg + (N_PTS / SPLITS);
    for (int j = jbeg; j < jend; j += 8) {
        float4 cc[8];
        #pragma unroll
        for (int u = 0; u < 8; ++u) cc[u] = pospp[j + u];
        #pragma unroll
        for (int u = 0; u < 8; ++u) {
            float dot = __fmaf_rn(qz, cc[u].z, __fmaf_rn(qy, cc[u].y, __fmul_rn(qx, cc[u].x)));
            float dd  = __fmaf_rn(-2.0f, dot, __fadd_rn(qq, cc[u].w));
            dd = fmaxf(dd, 0.0f);
            if (dd < d2) {                 // rare-taken; strict < = earliest index wins
                int jj = j + u;
                if (dd < d1) {
                    d2 = d1; i2 = i1;
                    if (dd < d0) { d1 = d0; i1 = i0; d0 = dd; i0 = jj; }
                    else         { d1 = dd; i1 = jj; }
                } else { d2 = dd; i2 = jj; }
            }
        }
    }
    sd[wv][lane][0] = d0; sd[wv][lane][1] = d1; sd[wv][lane][2] = d2;
    si[wv][lane][0] = i0; si[wv][lane][1] = i1; si[wv][lane][2] = i2;
    __syncthreads();

    if (threadIdx.x < 64) {
        const int t = threadIdx.x;
        float e0 = __builtin_inff(), e1 = __builtin_inff(), e2 = __builtin_inff();
        int   j0 = 0, j1 = 0, j2 = 0;
        #pragma unroll
        for (int ww = 0; ww < SPLITS; ++ww) {
            #pragma unroll
            for (int k = 0; k < 3; ++k) {
                float dd = sd[ww][t][k];
                int   jj = si[ww][t][k];
                if (dd < e2) {
                    if (dd < e1) {
                        e2 = e1; j2 = j1;
                        if (dd < e0) { e1 = e0; j1 = j0; e0 = dd; j0 = jj; }
                        else         { e1 = dd; j1 = jj; }
                    } else { e2 = dd; j2 = jj; }
                }
            }
        }
        float w0 = 1.0f / (e0 + 1e-16f);
        float w1 = 1.0f / (e1 + 1e-16f);
        float w2 = 1.0f / (e2 + 1e-16f);
        float inv = 1.0f / ((w0 + w1) + w2);
        wq[blockIdx.x * 64 + t] = make_float4(w0 * inv, w1 * inv, w2 * inv, 0.0f);
        iq[blockIdx.x * 64 + t] = make_int4(j0, j1, j2, 0);
    }
}

// ---------------- kernel 2: gather-interp + concat + MLP (bf16-split MFMA) ----------------
// LDS 40KB: Wh 16K | Wl 16K | Ah 4K | Al 4K. Linear layouts (64B row stride) are
// bank-conflict-free for both the 16B/lane staging sweeps and the MFMA frag reads.
__global__ __launch_bounds__(256, 3)
void mfma_mlp_kernel(const float* __restrict__ x,
                     const float* __restrict__ x_skip,
                     const float4* __restrict__ wq,
                     const int4*  __restrict__ iq,
                     const unsigned short* __restrict__ w1h, const unsigned short* __restrict__ w1l,
                     const unsigned short* __restrict__ w2h, const unsigned short* __restrict__ w2l,
                     const float* __restrict__ b1, const float* __restrict__ b2,
                     const float* __restrict__ pos_skip, const int* __restrict__ batch_skip,
                     float* __restrict__ out) {
    __shared__ unsigned short LB[20480];      // 40960 B
    unsigned short* Wh = LB;                  // 8192 shorts
    unsigned short* Wl = LB + 8192;           // 8192 shorts
    unsigned short* Ah = LB + 16384;          // 2048 shorts (64 rows x 32 k)
    unsigned short* Al = LB + 18432;          // 2048 shorts

    const int t    = threadIdx.x;
    const int lane = t & 63;
    const int w    = t >> 6;
    const int g    = lane >> 4;
    const int l15  = lane & 15;
    const int r0   = blockIdx.x * TMF;

    const int ar   = t >> 2;                  // A-stage row 0..63
    const int kg   = t & 3;                   // A-stage k-octet
    const int awi  = ar * 32 + kg * 8;        // short index

    const float4 wv = wq[r0 + ar];
    const int4   iv = iq[r0 + ar];

    // ---- GEMM1 acc, bias init ----
    f32x4 acc1[4][4];
    #pragma unroll
    for (int cb = 0; cb < 4; ++cb) {
        float bv = b1[w * 64 + cb * 16 + l15];
        #pragma unroll
        for (int rb = 0; rb < 4; ++rb) acc1[rb][cb] = (f32x4){bv, bv, bv, bv};
    }

    // ---- GEMM1: 12 chunks of K=32 ----
    for (int c = 0; c < NC1; ++c) {
        // A chunk: interp (cols<256) or skip copy; split; linear LDS write
        {
            float vvb[8];
            const int col0 = c * 32 + kg * 8;
            if (col0 < CX) {
                const float4* xa = (const float4*)&x[(size_t)iv.x * CX + col0];
                const float4* xb = (const float4*)&x[(size_t)iv.y * CX + col0];
                const float4* xc = (const float4*)&x[(size_t)iv.z * CX + col0];
                #pragma unroll
                for (int q4 = 0; q4 < 2; ++q4) {
                    float4 a4 = xa[q4], b4 = xb[q4], c4 = xc[q4];
                    vvb[q4 * 4 + 0] = (wv.x * a4.x + wv.y * b4.x) + wv.z * c4.x;
                    vvb[q4 * 4 + 1] = (wv.x * a4.y + wv.y * b4.y) + wv.z * c4.y;
                    vvb[q4 * 4 + 2] = (wv.x * a4.z + wv.y * b4.z) + wv.z * c4.z;
                    vvb[q4 * 4 + 3] = (wv.x * a4.w + wv.y * b4.w) + wv.z * c4.w;
                }
            } else {
                const float4* xs = (const float4*)&x_skip[(size_t)(r0 + ar) * CSK + (col0 - CX)];
                #pragma unroll
                for (int q4 = 0; q4 < 2; ++q4) {
                    float4 s4 = xs[q4];
                    vvb[q4 * 4 + 0] = s4.x; vvb[q4 * 4 + 1] = s4.y;
                    vvb[q4 * 4 + 2] = s4.z; vvb[q4 * 4 + 3] = s4.w;
                }
            }
            short8 hv, lv;
            #pragma unroll
            for (int e = 0; e < 8; ++e) {
                unsigned short hh = f2bf(vvb[e]);
                hv[e] = (short)hh;
                lv[e] = (short)f2bf(vvb[e] - bf2f(hh));
            }
            *(short8*)&Ah[awi] = hv;
            *(short8*)&Al[awi] = lv;
        }
        // W1 chunk: linear 16B/lane copy of the tiled layout
        {
            const int base = c * 8192 + t * 8;
            #pragma unroll
            for (int i = 0; i < 4; ++i) {
                *(short8*)&Wh[t * 8 + i * 2048] = *(const short8*)&w1h[base + i * 2048];
                *(short8*)&Wl[t * 8 + i * 2048] = *(const short8*)&w1l[base + i * 2048];
            }
        }
        __syncthreads();
        short8 ah[4], al[4];
        #pragma unroll
        for (int rb = 0; rb < 4; ++rb) {
            int ai = (rb * 16 + l15) * 32 + g * 8;
            ah[rb] = *(const short8*)&Ah[ai];
            al[rb] = *(const short8*)&Al[ai];
        }
        #pragma unroll
        for (int cb = 0; cb < 4; ++cb) {
            int bi = (w * 64 + cb * 16 + l15) * 32 + g * 8;
            short8 bh = *(const short8*)&Wh[bi];
            short8 bl = *(const short8*)&Wl[bi];
            #pragma unroll
            for (int rb = 0; rb < 4; ++rb) {
                acc1[rb][cb] = __builtin_amdgcn_mfma_f32_16x16x32_bf16(ah[rb], bh, acc1[rb][cb], 0, 0, 0);
                acc1[rb][cb] = __builtin_amdgcn_mfma_f32_16x16x32_bf16(al[rb], bh, acc1[rb][cb], 0, 0, 0);
                acc1[rb][cb] = __builtin_amdgcn_mfma_f32_16x16x32_bf16(ah[rb], bl, acc1[rb][cb], 0, 0, 0);
            }
        }
        __syncthreads();
    }

    // ---- relu + bf16(hi) pack of h1 (2-term GEMM2) ----
    unsigned int h1p[32];
    #pragma unroll
    for (int rb = 0; rb < 4; ++rb)
        #pragma unroll
        for (int cb = 0; cb < 4; ++cb)
            #pragma unroll
            for (int e = 0; e < 4; ++e) {
                int id = (rb * 4 + cb) * 4 + e;
                unsigned short hh = f2bf(fmaxf(acc1[rb][cb][e], 0.0f));
                if ((id & 1) == 0) h1p[id >> 1] = hh;
                else               h1p[id >> 1] |= ((unsigned int)hh) << 16;
            }

    // ---- GEMM2 acc, bias init ----
    f32x4 acc2[4][4];
    #pragma unroll
    for (int cb = 0; cb < 4; ++cb) {
        float bv = b2[w * 64 + cb * 16 + l15];
        #pragma unroll
        for (int rb = 0; rb < 4; ++rb) acc2[rb][cb] = (f32x4){bv, bv, bv, bv};
    }

    // ---- GEMM2: 8 chunks of K=32; chunk c's A-slice owned by wave c>>1 (half c&1) ----
    for (int c = 0; c < NC2; ++c) {
        {
            const int base = c * 8192 + t * 8;
            #pragma unroll
            for (int i = 0; i < 4; ++i) {
                *(short8*)&Wh[t * 8 + i * 2048] = *(const short8*)&w2h[base + i * 2048];
                *(short8*)&Wl[t * 8 + i * 2048] = *(const short8*)&w2l[base + i * 2048];
            }
        }
        if (w == (c >> 1)) {
            const int hf = c & 1;
            #pragma unroll
            for (int rb = 0; rb < 4; ++rb)
                #pragma unroll
                for (int cb2 = 0; cb2 < 2; ++cb2)
                    #pragma unroll
                    for (int e = 0; e < 4; ++e) {
                        int id = (rb * 4 + (2 * hf + cb2)) * 4 + e;
                        unsigned short hh = (unsigned short)(h1p[id >> 1] >> ((id & 1) * 16));
                        int row = rb * 16 + g * 4 + e;
                        Ah[row * 32 + cb2 * 16 + l15] = hh;
                    }
        }
        __syncthreads();
        short8 ah2[4];
        #pragma unroll
        for (int rb = 0; rb < 4; ++rb)
            ah2[rb] = *(const short8*)&Ah[(rb * 16 + l15) * 32 + g * 8];
        #pragma unroll
        for (int cb = 0; cb < 4; ++cb) {
            int bi = (w * 64 + cb * 16 + l15) * 32 + g * 8;
            short8 bh = *(const short8*)&Wh[bi];
            short8 bl = *(const short8*)&Wl[bi];
            #pragma unroll
            for (int rb = 0; rb < 4; ++rb) {
                acc2[rb][cb] = __builtin_amdgcn_mfma_f32_16x16x32_bf16(ah2[rb], bh, acc2[rb][cb], 0, 0, 0);
                acc2[rb][cb] = __builtin_amdgcn_mfma_f32_16x16x32_bf16(ah2[rb], bl, acc2[rb][cb], 0, 0, 0);
            }
        }
        __syncthreads();
    }

    // ---- epilogue: LDS transpose (stride 260) -> coalesced 128B/thread stores ----
    float* Cst = (float*)LB;     // 32 x 260 x 4B = 33280 B (W+A regions dead)
    #pragma unroll
    for (int r = 0; r < 2; ++r) {
        #pragma unroll
        for (int rbi = 0; rbi < 2; ++rbi) {
            int rb = 2 * r + rbi;
            #pragma unroll
            for (int cb = 0; cb < 4; ++cb)
                #pragma unroll
                for (int e = 0; e < 4; ++e) {
                    int lr = rbi * 16 + g * 4 + e;
                    Cst[lr * 260 + w * 64 + cb * 16 + l15] = acc2[rb][cb][e];
                }
        }
        __syncthreads();
        {
            int row = r0 + r * 32 + (t >> 3);
            const float* src = &Cst[(t >> 3) * 260 + (t & 7) * 32];
            float* dst = &out[(size_t)row * HD + (t & 7) * 32];
            #pragma unroll
            for (int j = 0; j < 8; ++j)
                ((float4*)dst)[j] = ((const float4*)src)[j];
        }
        __syncthreads();
    }

    if (t < TMF * 3)
        out[OUT_POS_OFF + blockIdx.x * (TMF * 3) + t] = pos_skip[blockIdx.x * (TMF * 3) + t];
    if (t < TMF)
        out[OUT_B_OFF + blockIdx.x * TMF + t] = (float)batch_skip[blockIdx.x * TMF + t];
}

// ---------------- launcher ----------------
extern "C" void kernel_launch(void* const* d_in, const int* in_sizes, int n_in,
                              void* d_out, int out_size, void* d_ws, size_t ws_size,
                              hipStream_t stream) {
    const float* x          = (const float*)d_in[0];
    const float* pos        = (const float*)d_in[1];
    const float* x_skip     = (const float*)d_in[3];
    const float* pos_skip   = (const float*)d_in[4];
    const int*   batch_skip = (const int*)d_in[5];
    const float* W1         = (const float*)d_in[6];
    const float* b1         = (const float*)d_in[7];
    const float* W2         = (const float*)d_in[8];
    const float* b2         = (const float*)d_in[9];
    float* out = (float*)d_out;

    char* ws = (char*)d_ws;
    float4* pospp        = (float4*)(ws);                   // 131072 B
    float4* wq           = (float4*)(ws + 131072);          // 524288 B
    int4*   iq           = (int4*)(ws + 655360);            // 524288 B
    unsigned short* w1h  = (unsigned short*)(ws + 1179648); // 196608 B
    unsigned short* w1l  = (unsigned short*)(ws + 1376256); // 196608 B
    unsigned short* w2h  = (unsigned short*)(ws + 1572864); // 131072 B
    unsigned short* w2l  = (unsigned short*)(ws + 1703936); // 131072 B -> ends 1835008

    prep_pp_kernel<<<N_PTS / 256, 256, 0, stream>>>(pos, pospp);
    prep_w_kernel<<<(256 * KD1 + 256 * 256 + 255) / 256, 256, 0, stream>>>(W1, W2, w1h, w1l, w2h, w2l);
    knn_kernel<<<M_PTS / 64, 1024, 0, stream>>>(pospp, pos_skip, wq, iq);
    mfma_mlp_kernel<<<M_PTS / TMF, 256, 0, stream>>>(x, x_skip, wq, iq,
                                                     w1h, w1l, w2h, w2l, b1, b2,
                                                     pos_skip, batch_skip, out);
}

// Round 6
// 238.386 us; speedup vs baseline: 2.2577x; 1.2447x over previous
//
#include <hip/hip_runtime.h>
#include <math.h>

#define N_PTS 8192
#define M_PTS 32768
#define CX    256
#define CSK   128
#define HD    256

#define OUT_POS_OFF (M_PTS * HD)              // 8388608
#define OUT_B_OFF   (OUT_POS_OFF + M_PTS * 3) // 8486912

#define SPLITS  16
#define TMF     32   // MLP rows per block
#define ASTRIDE 40   // shorts per A-tile row (80B: 2-way max on frag reads, 8B-aligned writes)
#define H1S     264  // shorts per H1 row (528B: 16B-aligned b128, ~2-way)
#define CSTS    260  // floats per Cst row

using short4v = __attribute__((ext_vector_type(4))) short;
using short8  = __attribute__((ext_vector_type(8))) short;
using f32x4   = __attribute__((ext_vector_type(4))) float;

__device__ __forceinline__ unsigned short f2bf(float f) {
    unsigned int u = __float_as_uint(f);
    return (unsigned short)((u + 0x7FFFu + ((u >> 16) & 1u)) >> 16);
}
__device__ __forceinline__ float bf2f(unsigned short h) {
    return __uint_as_float(((unsigned int)h) << 16);
}

// ---------------- kernel 0a: pack ref points + squared norms ----------------
__global__ __launch_bounds__(256)
void prep_pp_kernel(const float* __restrict__ pos, float4* __restrict__ pospp) {
    int j = blockIdx.x * 256 + threadIdx.x;
    if (j >= N_PTS) return;
    float x = pos[3 * j + 0], y = pos[3 * j + 1], z = pos[3 * j + 2];
    float pp = __fadd_rn(__fadd_rn(__fmul_rn(x, x), __fmul_rn(y, y)), __fmul_rn(z, z));
    pospp[j] = make_float4(x, y, z, pp);
}

// -------- kernel 0b: split W to bf16 hi/lo, tiled. W1:[12][256][32]  W2:[4][256][64] --------
__global__ __launch_bounds__(256)
void prep_w_kernel(const float* __restrict__ W1, const float* __restrict__ W2,
                   unsigned short* __restrict__ w1h, unsigned short* __restrict__ w1l,
                   unsigned short* __restrict__ w2h, unsigned short* __restrict__ w2l) {
    int id = blockIdx.x * 256 + threadIdx.x;
    if (id < 98304) {
        int c = id >> 13, rem = id & 8191, col = rem >> 5, kl = rem & 31;
        float v = W1[(c * 32 + kl) * HD + col];
        unsigned short h = f2bf(v);
        w1h[id] = h;
        w1l[id] = f2bf(v - bf2f(h));
    } else if (id < 98304 + 65536) {
        int id2 = id - 98304;
        int c = id2 >> 14, rem = id2 & 16383, col = rem >> 6, kl = rem & 63;
        float v = W2[(c * 64 + kl) * HD + col];
        unsigned short h = f2bf(v);
        w2h[id2] = h;
        w2l[id2] = f2bf(v - bf2f(h));
    }
}

// ------------- kernel 1: KNN top-3 (16-way split, per-wave LDS candidate tiles) -------------
__global__ __launch_bounds__(1024, 8)
void knn_kernel(const float4* __restrict__ pospp,
                const float*  __restrict__ pos_skip,
                float4* __restrict__ wq,
                int4*   __restrict__ iq) {
    __shared__ float4 tiles[SPLITS][64];     // 16 KB, wave-private slices
    __shared__ float sd[SPLITS][64][3];
    __shared__ int   si[SPLITS][64][3];
    const int lane = threadIdx.x & 63;
    const int wv   = threadIdx.x >> 6;
    const int q    = blockIdx.x * 64 + lane;

    const float qx = pos_skip[3 * q + 0];
    const float qy = pos_skip[3 * q + 1];
    const float qz = pos_skip[3 * q + 2];
    const float qq = __fadd_rn(__fadd_rn(__fmul_rn(qx, qx), __fmul_rn(qy, qy)), __fmul_rn(qz, qz));

    float d0 = __builtin_inff(), d1 = __builtin_inff(), d2 = __builtin_inff();
    int   i0 = 0, i1 = 0, i2 = 0;

    const int jbeg = wv * (N_PTS / SPLITS);          // 512-candidate slice
    const float4* src = pospp + jbeg;
    float4 nxt = src[lane];                          // stage tile 0
    tiles[wv][lane] = nxt;

    for (int tl = 0; tl < 8; ++tl) {
        if (tl < 7) nxt = src[(tl + 1) * 64 + lane]; // global load early (hidden under compute)
        const int jb2 = jbeg + tl * 64;
        #pragma unroll 4
        for (int u = 0; u < 64; ++u) {
            float4 c = tiles[wv][u];                 // uniform ds_read_b128 -> broadcast
            float dot = __fmaf_rn(qz, c.z, __fmaf_rn(qy, c.y, __fmul_rn(qx, c.x)));
            float dd  = __fmaf_rn(-2.0f, dot, __fadd_rn(qq, c.w));
            dd = fmaxf(dd, 0.0f);
            if (dd < d2) {                           // rare-taken; strict < = earliest index wins
                int jj = jb2 + u;
                if (dd < d1) {
                    d2 = d1; i2 = i1;
                    if (dd < d0) { d1 = d0; i1 = i0; d0 = dd; i0 = jj; }
                    else         { d1 = dd; i1 = jj; }
                } else { d2 = dd; i2 = jj; }
            }
        }
        if (tl < 7) tiles[wv][lane] = nxt;           // in-order DS: safe wave-private overwrite
    }
    sd[wv][lane][0] = d0; sd[wv][lane][1] = d1; sd[wv][lane][2] = d2;
    si[wv][lane][0] = i0; si[wv][lane][1] = i1; si[wv][lane][2] = i2;
    __syncthreads();

    if (threadIdx.x < 64) {
        const int t = threadIdx.x;
        float e0 = __builtin_inff(), e1 = __builtin_inff(), e2 = __builtin_inff();
        int   j0 = 0, j1 = 0, j2 = 0;
        #pragma unroll
        for (int ww = 0; ww < SPLITS; ++ww) {
            #pragma unroll
            for (int k = 0; k < 3; ++k) {
                float dd = sd[ww][t][k];
                int   jj = si[ww][t][k];
                if (dd < e2) {
                    if (dd < e1) {
                        e2 = e1; j2 = j1;
                        if (dd < e0) { e1 = e0; j1 = j0; e0 = dd; j0 = jj; }
                        else         { e1 = dd; j1 = jj; }
                    } else { e2 = dd; j2 = jj; }
                }
            }
        }
        float w0 = 1.0f / (e0 + 1e-16f);
        float w1 = 1.0f / (e1 + 1e-16f);
        float w2 = 1.0f / (e2 + 1e-16f);
        float inv = 1.0f / ((w0 + w1) + w2);
        wq[blockIdx.x * 64 + t] = make_float4(w0 * inv, w1 * inv, w2 * inv, 0.0f);
        iq[blockIdx.x * 64 + t] = make_int4(j0, j1, j2, 0);
    }
}

// ---------------- kernel 2: gather-interp + concat + MLP (bf16-split MFMA) ----------------
// W streamed straight from L2 (no intra-block reuse -> no LDS staging). LDS only for the
// double-buffered A tile (10KB), then H1 (16.5KB), then the transpose epilogue (33.3KB).
__global__ __launch_bounds__(256, 4)
void mfma_mlp_kernel(const float* __restrict__ x,
                     const float* __restrict__ x_skip,
                     const float4* __restrict__ wq,
                     const int4*  __restrict__ iq,
                     const unsigned short* __restrict__ w1h, const unsigned short* __restrict__ w1l,
                     const unsigned short* __restrict__ w2h, const unsigned short* __restrict__ w2l,
                     const float* __restrict__ b1, const float* __restrict__ b2,
                     const float* __restrict__ pos_skip, const int* __restrict__ batch_skip,
                     float* __restrict__ out) {
    __shared__ float LBf[8320];                          // 33280 B (union of phases)
    unsigned short* AH = (unsigned short*)LBf;           // [buf*2+hl][32*ASTRIDE]
    unsigned short* H1 = (unsigned short*)LBf;           // [32][H1S]
    float* Cst = LBf;                                    // [32][CSTS]

    const int t    = threadIdx.x;
    const int lane = t & 63;
    const int w    = t >> 6;
    const int g    = lane >> 4;
    const int l15  = lane & 15;
    const int r0   = blockIdx.x * TMF;

    const int ar  = t >> 3;                              // A-stage row 0..31
    const int kg8 = t & 7;                               // col quad
    const int awo = ar * ASTRIDE + kg8 * 4;

    const float4 wv4 = wq[r0 + ar];
    const int4   iv  = iq[r0 + ar];
    const float* xa = &x[(size_t)iv.x * CX];
    const float* xb = &x[(size_t)iv.y * CX];
    const float* xc = &x[(size_t)iv.z * CX];
    const float* xs = &x_skip[(size_t)(r0 + ar) * CSK];

    // ---- GEMM1 acc, bias init ----
    f32x4 acc1[2][4];
    #pragma unroll
    for (int cb = 0; cb < 4; ++cb) {
        float bv = b1[w * 64 + cb * 16 + l15];
        acc1[0][cb] = (f32x4){bv, bv, bv, bv};
        acc1[1][cb] = (f32x4){bv, bv, bv, bv};
    }

    // ---- prologue: stage chunk 0 (always interp region) ----
    {
        const int col0 = kg8 * 4;
        float4 a4 = *(const float4*)&xa[col0];
        float4 b4 = *(const float4*)&xb[col0];
        float4 c4 = *(const float4*)&xc[col0];
        float v[4];
        v[0] = (wv4.x * a4.x + wv4.y * b4.x) + wv4.z * c4.x;
        v[1] = (wv4.x * a4.y + wv4.y * b4.y) + wv4.z * c4.y;
        v[2] = (wv4.x * a4.z + wv4.y * b4.z) + wv4.z * c4.z;
        v[3] = (wv4.x * a4.w + wv4.y * b4.w) + wv4.z * c4.w;
        short4v hv, lv;
        #pragma unroll
        for (int e = 0; e < 4; ++e) {
            unsigned short hh = f2bf(v[e]);
            hv[e] = (short)hh;
            lv[e] = (short)f2bf(v[e] - bf2f(hh));
        }
        *(short4v*)&AH[0 * 1280 + awo] = hv;
        *(short4v*)&AH[1 * 1280 + awo] = lv;
    }
    __syncthreads();

    // ---- GEMM1: 12 chunks of K=32, A double-buffered, W direct from L2 ----
    const unsigned short* pb1h = w1h + (w * 64 + l15) * 32 + g * 8;
    const unsigned short* pb1l = w1l + (w * 64 + l15) * 32 + g * 8;
    for (int c = 0; c < 12; ++c) {
        const int buf = c & 1;
        const bool have = (c < 11);
        const int col0 = (c + 1) * 32 + kg8 * 4;
        float4 a4, b4, c4;
        if (have) {                                      // issue next-chunk loads early
            if (col0 < CX) {
                a4 = *(const float4*)&xa[col0];
                b4 = *(const float4*)&xb[col0];
                c4 = *(const float4*)&xc[col0];
            } else {
                a4 = *(const float4*)&xs[col0 - CX];
            }
        }
        // MFMA on buf
        short8 ah[2], al[2];
        #pragma unroll
        for (int rb = 0; rb < 2; ++rb) {
            int ao = (rb * 16 + l15) * ASTRIDE + g * 8;
            ah[rb] = *(const short8*)&AH[(buf * 2 + 0) * 1280 + ao];
            al[rb] = *(const short8*)&AH[(buf * 2 + 1) * 1280 + ao];
        }
        const unsigned short* ph = pb1h + c * 8192;
        const unsigned short* pl = pb1l + c * 8192;
        #pragma unroll
        for (int cb = 0; cb < 4; ++cb) {
            short8 bh = *(const short8*)&ph[cb * 512];
            short8 bl = *(const short8*)&pl[cb * 512];
            #pragma unroll
            for (int rb = 0; rb < 2; ++rb) {
                acc1[rb][cb] = __builtin_amdgcn_mfma_f32_16x16x32_bf16(ah[rb], bh, acc1[rb][cb], 0, 0, 0);
                acc1[rb][cb] = __builtin_amdgcn_mfma_f32_16x16x32_bf16(al[rb], bh, acc1[rb][cb], 0, 0, 0);
                acc1[rb][cb] = __builtin_amdgcn_mfma_f32_16x16x32_bf16(ah[rb], bl, acc1[rb][cb], 0, 0, 0);
            }
        }
        // convert + write chunk c+1 into buf^1
        if (have) {
            float v[4];
            if (col0 < CX) {
                v[0] = (wv4.x * a4.x + wv4.y * b4.x) + wv4.z * c4.x;
                v[1] = (wv4.x * a4.y + wv4.y * b4.y) + wv4.z * c4.y;
                v[2] = (wv4.x * a4.z + wv4.y * b4.z) + wv4.z * c4.z;
                v[3] = (wv4.x * a4.w + wv4.y * b4.w) + wv4.z * c4.w;
            } else {
                v[0] = a4.x; v[1] = a4.y; v[2] = a4.z; v[3] = a4.w;
            }
            short4v hv, lv;
            #pragma unroll
            for (int e = 0; e < 4; ++e) {
                unsigned short hh = f2bf(v[e]);
                hv[e] = (short)hh;
                lv[e] = (short)f2bf(v[e] - bf2f(hh));
            }
            *(short4v*)&AH[((buf ^ 1) * 2 + 0) * 1280 + awo] = hv;
            *(short4v*)&AH[((buf ^ 1) * 2 + 1) * 1280 + awo] = lv;
        }
        __syncthreads();
    }

    // ---- h1 = relu(acc1) -> bf16(hi) into H1 (whole 32x256 tile, once) ----
    #pragma unroll
    for (int rb = 0; rb < 2; ++rb)
        #pragma unroll
        for (int cb = 0; cb < 4; ++cb)
            #pragma unroll
            for (int e = 0; e < 4; ++e)
                H1[(rb * 16 + g * 4 + e) * H1S + w * 64 + cb * 16 + l15] =
                    f2bf(fmaxf(acc1[rb][cb][e], 0.0f));
    __syncthreads();

    // ---- GEMM2 acc, bias init ----
    f32x4 acc2[2][4];
    #pragma unroll
    for (int cb = 0; cb < 4; ++cb) {
        float bv = b2[w * 64 + cb * 16 + l15];
        acc2[0][cb] = (f32x4){bv, bv, bv, bv};
        acc2[1][cb] = (f32x4){bv, bv, bv, bv};
    }

    // ---- GEMM2: 4 chunks of K=64, barrier-free (H1 read-only), W2 direct from L2 ----
    const unsigned short* pb2h = w2h + (w * 64 + l15) * 64 + g * 8;
    const unsigned short* pb2l = w2l + (w * 64 + l15) * 64 + g * 8;
    #pragma unroll
    for (int c2 = 0; c2 < 4; ++c2) {
        short8 a2[2][2];
        #pragma unroll
        for (int rb = 0; rb < 2; ++rb)
            #pragma unroll
            for (int ks = 0; ks < 2; ++ks)
                a2[rb][ks] = *(const short8*)&H1[(rb * 16 + l15) * H1S + c2 * 64 + ks * 32 + g * 8];
        const unsigned short* ph = pb2h + c2 * 16384;
        const unsigned short* pl = pb2l + c2 * 16384;
        #pragma unroll
        for (int cb = 0; cb < 4; ++cb) {
            #pragma unroll
            for (int ks = 0; ks < 2; ++ks) {
                short8 bh = *(const short8*)&ph[cb * 1024 + ks * 32];
                short8 bl = *(const short8*)&pl[cb * 1024 + ks * 32];
                #pragma unroll
                for (int rb = 0; rb < 2; ++rb) {
                    acc2[rb][cb] = __builtin_amdgcn_mfma_f32_16x16x32_bf16(a2[rb][ks], bh, acc2[rb][cb], 0, 0, 0);
                    acc2[rb][cb] = __builtin_amdgcn_mfma_f32_16x16x32_bf16(a2[rb][ks], bl, acc2[rb][cb], 0, 0, 0);
                }
            }
        }
    }
    __syncthreads();

    // ---- epilogue: LDS transpose -> coalesced stores ----
    #pragma unroll
    for (int rb = 0; rb < 2; ++rb)
        #pragma unroll
        for (int cb = 0; cb < 4; ++cb)
            #pragma unroll
            for (int e = 0; e < 4; ++e)
                Cst[(rb * 16 + g * 4 + e) * CSTS + w * 64 + cb * 16 + l15] = acc2[rb][cb][e];
    __syncthreads();
    {
        const int row = t >> 3, seg = t & 7;
        const float* sp = &Cst[row * CSTS + seg * 32];
        float* dp = &out[(size_t)(r0 + row) * HD + seg * 32];
        #pragma unroll
        for (int j = 0; j < 8; ++j)
            ((float4*)dp)[j] = ((const float4*)sp)[j];
    }
    if (t < TMF * 3)
        out[OUT_POS_OFF + blockIdx.x * (TMF * 3) + t] = pos_skip[blockIdx.x * (TMF * 3) + t];
    if (t < TMF)
        out[OUT_B_OFF + blockIdx.x * TMF + t] = (float)batch_skip[blockIdx.x * TMF + t];
}

// ---------------- launcher ----------------
extern "C" void kernel_launch(void* const* d_in, const int* in_sizes, int n_in,
                              void* d_out, int out_size, void* d_ws, size_t ws_size,
                              hipStream_t stream) {
    const float* x          = (const float*)d_in[0];
    const float* pos        = (const float*)d_in[1];
    const float* x_skip     = (const float*)d_in[3];
    const float* pos_skip   = (const float*)d_in[4];
    const int*   batch_skip = (const int*)d_in[5];
    const float* W1         = (const float*)d_in[6];
    const float* b1         = (const float*)d_in[7];
    const float* W2         = (const float*)d_in[8];
    const float* b2         = (const float*)d_in[9];
    float* out = (float*)d_out;

    char* ws = (char*)d_ws;
    float4* pospp        = (float4*)(ws);                   // 131072 B
    float4* wq           = (float4*)(ws + 131072);          // 524288 B
    int4*   iq           = (int4*)(ws + 655360);            // 524288 B
    unsigned short* w1h  = (unsigned short*)(ws + 1179648); // 196608 B
    unsigned short* w1l  = (unsigned short*)(ws + 1376256); // 196608 B
    unsigned short* w2h  = (unsigned short*)(ws + 1572864); // 131072 B
    unsigned short* w2l  = (unsigned short*)(ws + 1703936); // 131072 B -> ends 1835008

    prep_pp_kernel<<<N_PTS / 256, 256, 0, stream>>>(pos, pospp);
    prep_w_kernel<<<640, 256, 0, stream>>>(W1, W2, w1h, w1l, w2h, w2l);
    knn_kernel<<<M_PTS / 64, 1024, 0, stream>>>(pospp, pos_skip, wq, iq);
    mfma_mlp_kernel<<<M_PTS / TMF, 256, 0, stream>>>(x, x_skip, wq, iq,
                                                     w1h, w1l, w2h, w2l, b1, b2,
                                                     pos_skip, batch_skip, out);
}